// Round 9
// baseline (299.481 us; speedup 1.0000x reference)
//
#include <hip/hip_runtime.h>
#include <cmath>

#define D 128
#define BM 128   // A rows per block tile (held in registers)
#define BN 64    // B cols per staged half-tile (LDS)
#define NSEG 12  // segments per strip-pair -> 64*12 = 768 blocks = 3/CU exactly
#define LOG2E 1.4426950408889634

typedef __attribute__((ext_vector_type(8))) _Float16 f16x8;
typedef __attribute__((ext_vector_type(4))) float f32x4;
typedef __attribute__((ext_vector_type(2))) float f32x2;

// async global->LDS 16B copy; LDS dst wave-uniform base + lane*16, swizzle
// lives in gsrc. R9/R10: builtin immediate ALWAYS 0; fold offsets into ptr.
__device__ __forceinline__ void async_cp16(const void* g, void* l) {
    __builtin_amdgcn_global_load_lds(
        (__attribute__((address_space(1))) void*)g,
        (__attribute__((address_space(3))) void*)l, 16, 0, 0);
}

// ---------------------------------------------------------------------------
// Prep: fp32 x -> fp16 (RTN) combined [x1; x2], per-row El[r] =
// -gamma*log2e*|row|^2 (log2-domain), AND zero the 64 acc slots (block 0).
// ---------------------------------------------------------------------------
__global__ __launch_bounds__(256) void prep_kernel(
    const float* __restrict__ x1, const float* __restrict__ x2,
    _Float16* __restrict__ xh, float* __restrict__ El,
    double* __restrict__ acc, float gl, int N) {
    int tid = threadIdx.x;
    if (blockIdx.x == 0 && tid < 64) acc[tid] = 0.0;
    int r = blockIdx.x * 16 + (tid >> 4);
    if (r >= 2 * N) return;
    int l = tid & 15;
    const float* row = (r < N) ? x1 + (size_t)r * D : x2 + (size_t)(r - N) * D;
    float4 v0 = ((const float4*)row)[l * 2];
    float4 v1 = ((const float4*)row)[l * 2 + 1];
    float v[8] = {v0.x, v0.y, v0.z, v0.w, v1.x, v1.y, v1.z, v1.w};
    float p = 0.f;
    _Float16 h8[8];
#pragma unroll
    for (int j = 0; j < 8; ++j) {
        p = fmaf(v[j], v[j], p);
        h8[j] = (_Float16)v[j];   // RTN-even
    }
    *(uint4*)(xh + (size_t)r * D + l * 8) = *(uint4*)h8;
#pragma unroll
    for (int off = 8; off; off >>= 1) p += __shfl_down(p, off, 16);
    if (l == 0) El[r] = gl * p;   // gl = -gamma*log2e
}

// ---------------------------------------------------------------------------
// R19: ABLATION, take 2. R18's probes ran but were FASTER than MODE0, so the
// top-5 (longest-dispatch) table hid them. e2e arithmetic recovered:
//   t1 + t2 = 59 +- 2 us;  skeleton S = (t1+t2) - t0 ~= 8.5 us;
//   Depi + Dmfma = 2*t0 - (t1+t2) ~= 42 us.  Split unknown -> this round.
// Fix: MODE1 (no-epilogue) probe runs REP=6 inner repeats -> 6*t1 in
// [150,290] us >> 50.7 -> occupies top-5. Readout: t1 = T/6.
//   Depi = 50.7 - t1;  Dmfma ~= 42 - Depi.
// Pre-registered R20 branch:
//   Depi >= 15 -> split-tj passes (in-tile MFMA||exp2 overlap, C 32->16);
//   Depi <  8 -> 32x32x16 MFMA shape (4x fewer issues, +20% FLOP/cy);
//   else both, tj-split first.
// MODE 0 (REP=1): R14 verbatim -> real acc. Tripwire: e2e - T ~= 107us.
// ---------------------------------------------------------------------------
template <int MODE, int REP>   // MODE: 0 = full, 1 = no-epilogue
__global__ __launch_bounds__(256, 3) void mmd_mfma_kernel(
    const _Float16* __restrict__ xh, const float* __restrict__ El,
    double* __restrict__ acc, float c2l, int N) {
    __shared__ float4 smem[2][1024];  // 32 KiB: two 16 KiB B half-buffers

    int tid = threadIdx.x;
    int lane = tid & 63, wave = tid >> 6;      // 4 waves
    int quad = lane >> 4, l16 = lane & 15;
    int wrow = (wave & 1) * 64;                // 2 row-groups of 64
    int wcol = (wave >> 1) * 32;               // 2 col-groups of 32

    int nt2 = 2 * N / BM;        // 128 combined block-rows
    int half = N / BM;           // first `half` are x1
    int p = blockIdx.x / NSEG;   // strip pair: rows p and nt2-1-p
    int s = blockIdx.x % NSEG;
    int tpp = nt2 + 1;           // tiles per pair (129)
    int q = tpp / NSEG, r = tpp % NSEG;
    int t0 = s * q + (s < r ? s : r);
    int nt = q + (s < r ? 1 : 0);    // 10 or 11 tiles
    int H = 2 * nt;                  // half-tiles (BN=64 cols each)

    // staging geometry: 16 KiB / 256 thr / 16 B = 4 slots/thread.
    int goff[4];
#pragma unroll
    for (int i = 0; i < 4; ++i) {
        int slot = i * 256 + tid;
        int row = slot >> 4;
        int g = (slot & 15) ^ (row & 7);
        goff[i] = row * D + g * 8;
    }

    auto stage = [&](int b2Base, int buf) {
        const _Float16* src = xh + (size_t)b2Base * D;
#pragma unroll
        for (int i = 0; i < 4; ++i)
            async_cp16(src + goff[i], &smem[buf][i * 256 + tid]);
    };
    auto BI = [&](int tt) { return tt <= p ? p : nt2 - 1 - p; };
    auto BJ = [&](int tt) { return tt <= p ? tt : tt - p - 1; };

    f16x8 a[4][4];       // A fragments: rows wrow..+64, full K=128 (64 VGPR)
    float4 ea4[4];       // A-side El (reloaded only on strip-row change)
    int curA = -1;
    double dsum = 0.0;

#pragma unroll 1
    for (int rp = 0; rp < REP; ++rp) {
        // prologue: halves 0 and 1 of tile t0 (rep-boundary: last ht of the
        // previous rep did vmcnt(0) + bottom s_barrier -> safe to restage)
        stage(BJ(t0) * BM, 0);
        stage(BJ(t0) * BM + BN, 1);

        for (int ht = 0; ht < H; ++ht) {
            int tt = t0 + (ht >> 1), h = ht & 1;
            int bi = BI(tt), bj = BJ(tt);
            int aBase = bi * BM;
            int bcolBase = bj * BM + h * BN;
            float w = (bi == bj) ? 1.0f : 2.0f;
            if ((bi < half) != (bj < half)) w = -2.0f;
            int cur = ht & 1;

            // counted wait: the 4 newest outstanding loads are stage(ht+1)'s;
            // everything older drains. NEVER vmcnt(0) mid-loop.
            if (ht + 1 < H) {
                asm volatile("s_waitcnt vmcnt(4)" ::: "memory");
            } else {
                asm volatile("s_waitcnt vmcnt(0)" ::: "memory");
            }
            __builtin_amdgcn_s_barrier();
            __builtin_amdgcn_sched_barrier(0);

            // B-side El (part of the epilogue -> removed in MODE 1)
            float ebv0 = 0.f, ebv1 = 0.f;
            if constexpr (MODE == 0) {
                int bcol0 = bcolBase + wcol + l16;
                ebv0 = El[bcol0];
                ebv1 = El[bcol0 + 16];
            }

            // A reload only when the strip row changes (<= 2x per block).
            if (aBase != curA) {
                curA = aBase;
#pragma unroll
                for (int u = 0; u < 4; ++u) {
                    int ar = aBase + wrow + u * 16 + l16;
#pragma unroll
                    for (int j = 0; j < 4; ++j) {
                        int g = (j >> 1) * 8 + (j & 1) * 4 + quad;
                        a[u][j] = *(const f16x8*)(xh + (size_t)ar * D + g * 8);
                    }
                }
                int arow0 = aBase + wrow + quad * 4;
#pragma unroll
                for (int ti = 0; ti < 4; ++ti)
                    ea4[ti] = *(const float4*)&El[arow0 + ti * 16];
            }
            __builtin_amdgcn_sched_barrier(0);  // loads issued before MFMAs

            f32x4 C[4][2];
#pragma unroll
            for (int ti = 0; ti < 4; ++ti)
#pragma unroll
                for (int tj = 0; tj < 2; ++tj) C[ti][tj] = {0.f, 0.f, 0.f, 0.f};

            __builtin_amdgcn_s_setprio(1);
#pragma unroll
            for (int j = 0; j < 4; ++j) {
                int gb = (j >> 1) * 8 + (j & 1) * 4 + quad;
                f16x8 b[2];
#pragma unroll
                for (int u = 0; u < 2; ++u) {
                    int br = wcol + u * 16 + l16;
                    b[u] = *(const f16x8*)&smem[cur][br * 16 + (gb ^ (br & 7))];
                }
#pragma unroll
                for (int ti = 0; ti < 4; ++ti)
#pragma unroll
                    for (int tj = 0; tj < 2; ++tj)
                        C[ti][tj] = __builtin_amdgcn_mfma_f32_16x16x32_f16(
                            a[ti][j], b[tj], C[ti][tj], 0, 0, 0);
            }
            __builtin_amdgcn_s_setprio(0);

            if constexpr (MODE == 0) {
                // full epilogue: entry = exp2(c2l*d + ea) * 2^eb
                // C/D layout (m89-verified): col = lane&15, row = quad*4+reg.
                f32x2 cc = {c2l, c2l};
                float lsum = 0.f;
#pragma unroll
                for (int tj = 0; tj < 2; ++tj) {
                    f32x2 p2 = {0.f, 0.f};
#pragma unroll
                    for (int ti = 0; ti < 4; ++ti) {
                        f32x4 d = C[ti][tj];
                        f32x2 a01 = cc * f32x2{d.x, d.y} + f32x2{ea4[ti].x, ea4[ti].y};
                        f32x2 a23 = cc * f32x2{d.z, d.w} + f32x2{ea4[ti].z, ea4[ti].w};
                        f32x2 e, e2;
                        e.x = __builtin_amdgcn_exp2f(a01.x);
                        e.y = __builtin_amdgcn_exp2f(a01.y);
                        e2.x = __builtin_amdgcn_exp2f(a23.x);
                        e2.y = __builtin_amdgcn_exp2f(a23.y);
                        p2 += e + e2;
                    }
                    lsum = fmaf(p2.x + p2.y,
                                __builtin_amdgcn_exp2f(tj ? ebv1 : ebv0), lsum);
                }
                dsum += (double)lsum * (double)w;
            } else {
                // MODE 1: consume C with plain adds (keeps MFMAs live, no
                // trans-pipe, no El traffic -- rule 17)
                f32x2 p2t = {0.f, 0.f};
#pragma unroll
                for (int tj = 0; tj < 2; ++tj)
#pragma unroll
                    for (int ti = 0; ti < 4; ++ti) {
                        f32x4 d = C[ti][tj];
                        p2t += f32x2{d.x, d.y};
                        p2t += f32x2{d.z, d.w};
                    }
                dsum += (double)(p2t.x + p2t.y) * (double)w;
            }

            // all waves done reading buf[cur] -> overwrite with ht+2
            __builtin_amdgcn_sched_barrier(0);
            __builtin_amdgcn_s_barrier();
            __builtin_amdgcn_sched_barrier(0);
            if (ht + 2 < H) {
                int tn = t0 + ((ht + 2) >> 1);     // (ht+2)&1 == h
                stage(BJ(tn) * BM + h * BN, cur);
            }
        }
    }

    // block reduction (once per block)
#pragma unroll
    for (int off = 32; off; off >>= 1) dsum += __shfl_down(dsum, off);
    double* red = (double*)&smem[0][0];
    if (lane == 0) red[wave] = dsum;
    __syncthreads();
    if (tid == 0)
        atomicAdd(&acc[blockIdx.x & 63], red[0] + red[1] + red[2] + red[3]);
}

// ---------------------------------------------------------------------------
// Finalize: out = sqrt(max(S/N^2, 0)), S already = S11 + S22 - 2*S12.
// ---------------------------------------------------------------------------
__global__ __launch_bounds__(64) void mmd_finalize_kernel(
    const double* __restrict__ acc, float* __restrict__ out, int N) {
    int l = threadIdx.x;
    double v = acc[l];
#pragma unroll
    for (int off = 32; off; off >>= 1) v += __shfl_down(v, off);
    if (l == 0) {
        double nn = (double)N * (double)N;
        double s = v / nn;
        out[0] = (float)sqrt(s > 0.0 ? s : 0.0);
    }
}

extern "C" void kernel_launch(void* const* d_in, const int* in_sizes, int n_in,
                              void* d_out, int out_size, void* d_ws, size_t ws_size,
                              hipStream_t stream) {
    const float* x1 = (const float*)d_in[0];
    const float* x2 = (const float*)d_in[1];
    int N = in_sizes[0] / D;  // 8192

    // ws layout: [0,512) real acc (64 doubles); [512,1024) probe acc;
    // El @8192 (2N f32); xh @73728 (4 MB).
    double* acc = (double*)d_ws;
    float* El = (float*)((char*)d_ws + 8192);
    _Float16* xh = (_Float16*)((char*)d_ws + 73728);

    double lg = lgamma(0.5 * (D + 1)) - lgamma(0.5 * D);
    double gz = 2.0 * exp(lg);
    double gamma = 1.0 / (2.0 * gz * gz);
    float gl = (float)(-gamma * LOG2E);        // El scale
    float c2l = (float)(2.0 * gamma * LOG2E);  // dot scale (log2 domain)

    prep_kernel<<<(2 * N + 15) / 16, 256, 0, stream>>>(x1, x2, xh, El, acc, gl, N);

    int nblocks = 64 * NSEG;   // 768 blocks = 3/CU

    // real kernel + finalize first (output correctness independent of probe)
    mmd_mfma_kernel<0, 1><<<nblocks, 256, 0, stream>>>(xh, El, acc, c2l, N);
    mmd_finalize_kernel<<<1, 64, 0, stream>>>(acc, (float*)d_out, N);

    // no-epilogue probe, 6x repeat -> lands in top-5; t1 = dur/6
    mmd_mfma_kernel<1, 6><<<nblocks, 256, 0, stream>>>(xh, El, acc + 64, c2l, N);
}

// Round 10
// 105.601 us; speedup vs baseline: 2.8360x; 2.8360x over previous
//
#include <hip/hip_runtime.h>
#include <cmath>

#define D 128
#define BM 128   // A rows per block tile (held in registers)
#define BN 64    // B cols per staged half-tile (LDS)
#define NSEG 12  // segments per strip-pair -> 64*12 = 768 blocks = 3/CU exactly
#define LOG2E 1.4426950408889634

typedef __attribute__((ext_vector_type(8))) _Float16 f16x8;
typedef __attribute__((ext_vector_type(4))) float f32x4;
typedef __attribute__((ext_vector_type(2))) float f32x2;

// async global->LDS 16B copy; LDS dst wave-uniform base + lane*16, swizzle
// lives in gsrc. R9/R10: builtin immediate ALWAYS 0; fold offsets into ptr.
__device__ __forceinline__ void async_cp16(const void* g, void* l) {
    __builtin_amdgcn_global_load_lds(
        (__attribute__((address_space(1))) void*)g,
        (__attribute__((address_space(3))) void*)l, 16, 0, 0);
}

// ---------------------------------------------------------------------------
// Prep: fp32 x -> fp16 (RTN) combined [x1; x2], per-row El[r] =
// -gamma*log2e*|row|^2 (log2-domain), AND zero the 64 acc slots (block 0).
// ---------------------------------------------------------------------------
__global__ __launch_bounds__(256) void prep_kernel(
    const float* __restrict__ x1, const float* __restrict__ x2,
    _Float16* __restrict__ xh, float* __restrict__ El,
    double* __restrict__ acc, float gl, int N) {
    int tid = threadIdx.x;
    if (blockIdx.x == 0 && tid < 64) acc[tid] = 0.0;
    int r = blockIdx.x * 16 + (tid >> 4);
    if (r >= 2 * N) return;
    int l = tid & 15;
    const float* row = (r < N) ? x1 + (size_t)r * D : x2 + (size_t)(r - N) * D;
    float4 v0 = ((const float4*)row)[l * 2];
    float4 v1 = ((const float4*)row)[l * 2 + 1];
    float v[8] = {v0.x, v0.y, v0.z, v0.w, v1.x, v1.y, v1.z, v1.w};
    float p = 0.f;
    _Float16 h8[8];
#pragma unroll
    for (int j = 0; j < 8; ++j) {
        p = fmaf(v[j], v[j], p);
        h8[j] = (_Float16)v[j];   // RTN-even
    }
    *(uint4*)(xh + (size_t)r * D + l * 8) = *(uint4*)h8;
#pragma unroll
    for (int off = 8; off; off >>= 1) p += __shfl_down(p, off, 16);
    if (l == 0) El[r] = gl * p;   // gl = -gamma*log2e
}

// ---------------------------------------------------------------------------
// R20: split-tj MFMA||epilogue overlap (pre-registered from R18/R19 ablation:
// t0=50.7, t1(no-epi)=33.3 -> Depi=17.4us; skeleton 8.5; MFMA marginal ~24).
// The epilogue costs 17.4us serial but only ~11.7us of pipe time -- it runs
// strictly AFTER the MFMAs (C-accumulator RAW). C[ti][0] and C[ti][1] are
// independent column-halves, so:
//   Phase A: 4x{ds_read b0, 4 MFMA -> C0}         (matrix pipe)
//   Phase B: 4x{ds_read b1, 4 MFMA -> C1, epi-chunk of C0[j]}
//            -- C0's 16 exp2 + VALU issue while C1's MFMAs occupy the
//               matrix pipe (different pipes, no reg deps).
//   Tail:    epi of C1 only (~half the old exposure).
// ZERO extra registers vs R14 (C stays 32; pure reorder). Skeleton, staging,
// A-in-regs, counted vmcnt(4), barriers: R14 verbatim (50.7us, absmax 0.0).
// Predicted: 42-45us main, MfmaUtil 29-33%. Fallback if <=1us gain:
// force interleave with sched_group_barrier (R21), else axis abandoned.
// Tripwires: WRITE_SIZE KB-scale, VGPR 80-110, bank conflict ~2.1M.
// Signed weight: bi==bj: +1; same class off-diag: +2; cross class: -2.
// MFMA: v_mfma_f32_16x16x32_f16 (m89/m91-HW-verified C/D layout:
// col = lane&15, row = quad*4 + reg).
// ---------------------------------------------------------------------------
__global__ __launch_bounds__(256, 3) void mmd_mfma_kernel(
    const _Float16* __restrict__ xh, const float* __restrict__ El,
    double* __restrict__ acc, float c2l, int N) {
    __shared__ float4 smem[2][1024];  // 32 KiB: two 16 KiB B half-buffers

    int tid = threadIdx.x;
    int lane = tid & 63, wave = tid >> 6;      // 4 waves
    int quad = lane >> 4, l16 = lane & 15;
    int wrow = (wave & 1) * 64;                // 2 row-groups of 64
    int wcol = (wave >> 1) * 32;               // 2 col-groups of 32

    int nt2 = 2 * N / BM;        // 128 combined block-rows
    int half = N / BM;           // first `half` are x1
    int p = blockIdx.x / NSEG;   // strip pair: rows p and nt2-1-p
    int s = blockIdx.x % NSEG;
    int tpp = nt2 + 1;           // tiles per pair (129)
    int q = tpp / NSEG, r = tpp % NSEG;
    int t0 = s * q + (s < r ? s : r);
    int nt = q + (s < r ? 1 : 0);    // 10 or 11 tiles
    int H = 2 * nt;                  // half-tiles (BN=64 cols each)

    // staging geometry: 16 KiB / 256 thr / 16 B = 4 slots/thread.
    int goff[4];
#pragma unroll
    for (int i = 0; i < 4; ++i) {
        int slot = i * 256 + tid;
        int row = slot >> 4;
        int g = (slot & 15) ^ (row & 7);
        goff[i] = row * D + g * 8;
    }

    auto stage = [&](int b2Base, int buf) {
        const _Float16* src = xh + (size_t)b2Base * D;
#pragma unroll
        for (int i = 0; i < 4; ++i)
            async_cp16(src + goff[i], &smem[buf][i * 256 + tid]);
    };
    auto BI = [&](int tt) { return tt <= p ? p : nt2 - 1 - p; };
    auto BJ = [&](int tt) { return tt <= p ? tt : tt - p - 1; };

    // prologue: halves 0 and 1 of tile t0
    stage(BJ(t0) * BM, 0);
    stage(BJ(t0) * BM + BN, 1);

    f16x8 a[4][4];       // A fragments: rows wrow..+64, full K=128 (64 VGPR)
    float4 ea4[4];       // A-side El (reloaded only on strip-row change)
    int curA = -1;
    double dsum = 0.0;
    f32x2 cc = {c2l, c2l};

    for (int ht = 0; ht < H; ++ht) {
        int tt = t0 + (ht >> 1), h = ht & 1;
        int bi = BI(tt), bj = BJ(tt);
        int aBase = bi * BM;
        int bcolBase = bj * BM + h * BN;
        float w = (bi == bj) ? 1.0f : 2.0f;
        if ((bi < half) != (bj < half)) w = -2.0f;
        int cur = ht & 1;

        // counted wait: the 4 newest outstanding loads are stage(ht+1)'s;
        // everything older drains. NEVER vmcnt(0) mid-loop.
        if (ht + 1 < H) {
            asm volatile("s_waitcnt vmcnt(4)" ::: "memory");
        } else {
            asm volatile("s_waitcnt vmcnt(0)" ::: "memory");
        }
        __builtin_amdgcn_s_barrier();
        __builtin_amdgcn_sched_barrier(0);

        // B-side El for THIS half-tile
        int bcol0 = bcolBase + wcol + l16;
        float ebv0 = El[bcol0];
        float ebv1 = El[bcol0 + 16];

        // A reload only when the strip row changes (<= 2x per block).
        if (aBase != curA) {
            curA = aBase;
#pragma unroll
            for (int u = 0; u < 4; ++u) {
                int ar = aBase + wrow + u * 16 + l16;
#pragma unroll
                for (int j = 0; j < 4; ++j) {
                    int g = (j >> 1) * 8 + (j & 1) * 4 + quad;
                    a[u][j] = *(const f16x8*)(xh + (size_t)ar * D + g * 8);
                }
            }
            int arow0 = aBase + wrow + quad * 4;
#pragma unroll
            for (int ti = 0; ti < 4; ++ti)
                ea4[ti] = *(const float4*)&El[arow0 + ti * 16];
        }
        __builtin_amdgcn_sched_barrier(0);  // loads issued before MFMA phase

        f32x4 C0[4], C1[4];
#pragma unroll
        for (int ti = 0; ti < 4; ++ti) {
            C0[ti] = {0.f, 0.f, 0.f, 0.f};
            C1[ti] = {0.f, 0.f, 0.f, 0.f};
        }

        __builtin_amdgcn_s_setprio(1);
        // ---- Phase A: column-half 0 MFMAs (matrix pipe fills) ----
#pragma unroll
        for (int j = 0; j < 4; ++j) {
            int gb = (j >> 1) * 8 + (j & 1) * 4 + quad;
            int br0 = wcol + l16;
            f16x8 b0 = *(const f16x8*)&smem[cur][br0 * 16 + (gb ^ (br0 & 7))];
#pragma unroll
            for (int ti = 0; ti < 4; ++ti)
                C0[ti] = __builtin_amdgcn_mfma_f32_16x16x32_f16(
                    a[ti][j], b0, C0[ti], 0, 0, 0);
        }
        // ---- Phase B: column-half 1 MFMAs, C0's epilogue in their shadow.
        // Per j: 1 ds_read + 4 MFMA (matrix) + 8 exp2 + VALU (trans/VALU).
        // No register deps between the two streams -> co-issue.
        f32x2 p20 = {0.f, 0.f};
#pragma unroll
        for (int j = 0; j < 4; ++j) {
            int gb = (j >> 1) * 8 + (j & 1) * 4 + quad;
            int br1 = wcol + 16 + l16;
            f16x8 b1 = *(const f16x8*)&smem[cur][br1 * 16 + (gb ^ (br1 & 7))];
#pragma unroll
            for (int ti = 0; ti < 4; ++ti)
                C1[ti] = __builtin_amdgcn_mfma_f32_16x16x32_f16(
                    a[ti][j], b1, C1[ti], 0, 0, 0);
            // epi-chunk of C0[j] (C0 complete since end of Phase A)
            f32x4 d = C0[j];
            f32x2 a01 = cc * f32x2{d.x, d.y} + f32x2{ea4[j].x, ea4[j].y};
            f32x2 a23 = cc * f32x2{d.z, d.w} + f32x2{ea4[j].z, ea4[j].w};
            f32x2 e, e2;
            e.x = __builtin_amdgcn_exp2f(a01.x);
            e.y = __builtin_amdgcn_exp2f(a01.y);
            e2.x = __builtin_amdgcn_exp2f(a23.x);
            e2.y = __builtin_amdgcn_exp2f(a23.y);
            p20 += e + e2;
        }
        __builtin_amdgcn_s_setprio(0);
        float lsum = (p20.x + p20.y) * __builtin_amdgcn_exp2f(ebv0);

        // ---- Tail: C1's epilogue (the only exposed half now) ----
        f32x2 p21 = {0.f, 0.f};
#pragma unroll
        for (int j = 0; j < 4; ++j) {
            f32x4 d = C1[j];
            f32x2 a01 = cc * f32x2{d.x, d.y} + f32x2{ea4[j].x, ea4[j].y};
            f32x2 a23 = cc * f32x2{d.z, d.w} + f32x2{ea4[j].z, ea4[j].w};
            f32x2 e, e2;
            e.x = __builtin_amdgcn_exp2f(a01.x);
            e.y = __builtin_amdgcn_exp2f(a01.y);
            e2.x = __builtin_amdgcn_exp2f(a23.x);
            e2.y = __builtin_amdgcn_exp2f(a23.y);
            p21 += e + e2;
        }
        lsum = fmaf(p21.x + p21.y, __builtin_amdgcn_exp2f(ebv1), lsum);
        dsum += (double)lsum * (double)w;

        // all waves done reading buf[cur] -> overwrite with half-tile ht+2
        __builtin_amdgcn_sched_barrier(0);
        __builtin_amdgcn_s_barrier();
        __builtin_amdgcn_sched_barrier(0);
        if (ht + 2 < H) {
            int tn = t0 + ((ht + 2) >> 1);     // (ht+2)&1 == h
            stage(BJ(tn) * BM + h * BN, cur);
        }
    }

    // block reduction (once per block)
#pragma unroll
    for (int off = 32; off; off >>= 1) dsum += __shfl_down(dsum, off);
    double* red = (double*)&smem[0][0];
    if (lane == 0) red[wave] = dsum;
    __syncthreads();
    if (tid == 0)
        atomicAdd(&acc[blockIdx.x & 63], red[0] + red[1] + red[2] + red[3]);
}

// ---------------------------------------------------------------------------
// Finalize: out = sqrt(max(S/N^2, 0)), S already = S11 + S22 - 2*S12.
// ---------------------------------------------------------------------------
__global__ __launch_bounds__(64) void mmd_finalize_kernel(
    const double* __restrict__ acc, float* __restrict__ out, int N) {
    int l = threadIdx.x;
    double v = acc[l];
#pragma unroll
    for (int off = 32; off; off >>= 1) v += __shfl_down(v, off);
    if (l == 0) {
        double nn = (double)N * (double)N;
        double s = v / nn;
        out[0] = (float)sqrt(s > 0.0 ? s : 0.0);
    }
}

extern "C" void kernel_launch(void* const* d_in, const int* in_sizes, int n_in,
                              void* d_out, int out_size, void* d_ws, size_t ws_size,
                              hipStream_t stream) {
    const float* x1 = (const float*)d_in[0];
    const float* x2 = (const float*)d_in[1];
    int N = in_sizes[0] / D;  // 8192

    // ws layout: [0,512) acc (64 doubles); El @8192 (2N f32);
    // xh @73728 (2N*128 fp16 = 4 MB). Total ~4.07 MB.
    double* acc = (double*)d_ws;
    float* El = (float*)((char*)d_ws + 8192);
    _Float16* xh = (_Float16*)((char*)d_ws + 73728);

    double lg = lgamma(0.5 * (D + 1)) - lgamma(0.5 * D);
    double gz = 2.0 * exp(lg);
    double gamma = 1.0 / (2.0 * gz * gz);
    float gl = (float)(-gamma * LOG2E);        // El scale
    float c2l = (float)(2.0 * gamma * LOG2E);  // dot scale (log2 domain)

    prep_kernel<<<(2 * N + 15) / 16, 256, 0, stream>>>(x1, x2, xh, El, acc, gl, N);

    int nblocks = 64 * NSEG;   // 64 strip-pairs x 12 segments = 768 = 3/CU
    mmd_mfma_kernel<<<nblocks, 256, 0, stream>>>(xh, El, acc, c2l, N);

    mmd_finalize_kernel<<<1, 64, 0, stream>>>(acc, (float*)d_out, N);
}